// Round 9
// baseline (281.466 us; speedup 1.0000x reference)
//
#include <hip/hip_runtime.h>
#include <hip/hip_bf16.h>

#define NN 32
#define CIN 64
#define TTOT 300
#define VV 25
#define PP 3
#define COUT 128
#define KTOT 192     // P*CIN
#define TTILE 5
#define NTILES 60
#define CNT 240000.0f
#define NCOLS 240000 // N*T*V
#define NBLK 1920    // agg grid
#define SBLK 1875    // conv_stats grid (128-col blocks)
#define ABLK 7500    // conv_apply grid (32-col blocks)

#define XSTR 40      // fallback path stride
#define ZSTR 72
#define ZROWS 128

// ws float offsets (front region)
#define WS_STATS 0    // 256 f32 (fallback path only)
#define WS_SCALE 256  // 128 f32
#define WS_SHIFT 384  // 128 f32
#define WS_BSUM  512  // 128 f32
#define WS_W2    640  // bf16[128*192]; W2[o][p*64+c]
#define WS_AT    16384            // bf16[3*32*40] At table (zero-padded)
#define WS_PART  32768            // f32[1875][256] partials (~1.9 MB, ends < 4MB)
#define ZT_BYTE_OFF (4u << 20)    // Zt bf16[240000][192] at +4MB
#define WS_NEEDED (ZT_BYTE_OFF + (size_t)NCOLS * KTOT * 2)

typedef float f32x4 __attribute__((ext_vector_type(4)));
typedef short s16x8 __attribute__((ext_vector_type(8)));

__device__ __forceinline__ short f2bf(float f) {
    unsigned u = __float_as_uint(f);
    u += 0x7fff + ((u >> 16) & 1);          // RNE
    return (short)(u >> 16);
}

__global__ __launch_bounds__(256) void prep_kernel(const float* __restrict__ W,
                                                   const float* __restrict__ A,
                                                   const float* __restrict__ b,
                                                   float* __restrict__ ws) {
    int tid = blockIdx.x * blockDim.x + threadIdx.x;
    if (tid < 256) ws[WS_STATS + tid] = 0.0f;               // fallback path zeroing
    if (tid >= 256 && tid < 384) {
        int o = tid - 256;
        ws[WS_BSUM + o] = b[o] + b[COUT + o] + b[2 * COUT + o];
    }
    if (tid < COUT * KTOT) {                                 // W2[o][k], k = p*64+c
        int o = tid / KTOT, k = tid % KTOT;
        int p = k / 64, c = k % 64;
        ((short*)(ws + WS_W2))[tid] = f2bf(W[(p * COUT + o) * CIN + c]);
    }
    if (tid < PP * 32 * XSTR) {                              // At[p][v][w], zero-padded
        int p = tid / (32 * XSTR);
        int r = tid - p * (32 * XSTR);
        int v = r / XSTR, w = r - v * XSTR;
        ((short*)(ws + WS_AT))[tid] =
            (v < VV && w < VV) ? f2bf(A[p * (VV * VV) + w * VV + v]) : (short)0;
    }
}

// ---------------- fast path ----------------

// agg_v2: x -> Zt only. One barrier; f32 LDS tile (XOR-swizzled); A-frags from ws.
__global__ __launch_bounds__(512, 4) void agg_v2(const float* __restrict__ x,
                                                 const float* __restrict__ ws,
                                                 short* __restrict__ Zt) {
    __shared__ __align__(16) float XF[TTILE * 64 * 32];     // 40960 B, rows 128B

    const int tid  = threadIdx.x;
    const int lane = tid & 63;
    const int wave = tid >> 6;
    const int n  = blockIdx.x / NTILES;
    const int t0 = (blockIdx.x % NTILES) * TTILE;
    const int lg = lane >> 4;
    const int li = lane & 15;

    {   // stage x raw f32, swizzled; w>=25 zeroed (K-pad)
        const float* xb = x + (size_t)n * (CIN * TTOT * VV) + (size_t)t0 * VV;
        #pragma unroll
        for (int it = 0; it < 20; ++it) {                   // 20*512 = 64*5*32
            int i = tid + it * 512;
            int c = i / 160;
            int r2 = i - c * 160;
            int t = r2 >> 5, w = r2 & 31;
            float val = (w < VV) ? xb[c * (TTOT * VV) + t * VV + w] : 0.0f;
            int row = t * 64 + c;
            int byte = ((row * 32 + w) * 4) ^ ((row & 7) << 4);
            *(float*)((char*)XF + byte) = val;
        }
    }
    __syncthreads();

    const int acf = wave >> 1;         // c-frag 0..3
    const int avf = wave & 1;          // v-frag 0..1
    const int vv  = avf * 16 + li;

    s16x8 xa[TTILE];
    #pragma unroll
    for (int t = 0; t < TTILE; ++t) {
        int row = t * 64 + acf * 16 + li;
        int sw = (row & 7) << 4;
        f32x4 lo = *(const f32x4*)((const char*)XF + ((row * 128 + lg * 32) ^ sw));
        f32x4 hi = *(const f32x4*)((const char*)XF + ((row * 128 + lg * 32 + 16) ^ sw));
        s16x8 v;
        v[0] = f2bf(lo[0]); v[1] = f2bf(lo[1]); v[2] = f2bf(lo[2]); v[3] = f2bf(lo[3]);
        v[4] = f2bf(hi[0]); v[5] = f2bf(hi[1]); v[6] = f2bf(hi[2]); v[7] = f2bf(hi[3]);
        xa[t] = v;
    }
    const short* at = (const short*)(ws + WS_AT);
    s16x8 af[PP];
    #pragma unroll
    for (int p = 0; p < PP; ++p)
        af[p] = *(const s16x8*)(at + (p * 32 + avf * 16 + li) * XSTR + lg * 8);

    const bool vok = (vv < VV);
    const size_t colbase = (size_t)n * 7500 + (size_t)t0 * VV + vv;
    const int kbase = acf * 16 + lg * 4;
    #pragma unroll
    for (int t = 0; t < TTILE; ++t) {
        #pragma unroll
        for (int p = 0; p < PP; ++p) {
            f32x4 z = (f32x4){0.f, 0.f, 0.f, 0.f};
            f32x4 d = __builtin_amdgcn_mfma_f32_16x16x32_bf16(xa[t], af[p], z, 0, 0, 0);
            if (vok) {
                ushort4 pk;
                pk.x = (unsigned short)f2bf(d[0]);
                pk.y = (unsigned short)f2bf(d[1]);
                pk.z = (unsigned short)f2bf(d[2]);
                pk.w = (unsigned short)f2bf(d[3]);
                *(ushort4*)(&Zt[(colbase + (size_t)t * VV) * KTOT + p * 64 + kbase]) = pk;
            }
        }
    }
}

// conv_stats: Zt -> per-block partial sum/sumsq. ALL 24 Z fragments loaded into
// named registers BEFORE any MFMA (one vmcnt wait per wave). LB(512,2): VGPR cap
// 256 so the scheduler keeps the loads hoisted. No y write, no global atomics.
__global__ __launch_bounds__(512, 2) void conv_stats(const short* __restrict__ Zt,
                                                     float* __restrict__ ws) {
    __shared__ float sstat[256];
    const int tid  = threadIdx.x;
    const int lane = tid & 63;
    const int wave = tid >> 6;
    const int lg = lane >> 4;
    const int li = lane & 15;
    const int c0 = blockIdx.x * 128;
    const int ow = wave >> 1;
    const int ch = wave & 1;
    const int o0 = ow * 32;

    if (tid < 256) sstat[tid] = 0.0f;

    const short* w2 = (const short*)(ws + WS_W2);
    s16x8 wf[2][6];
    #pragma unroll
    for (int mf = 0; mf < 2; ++mf)
        #pragma unroll
        for (int ks = 0; ks < 6; ++ks)
            wf[mf][ks] = *(const s16x8*)(w2 + (o0 + mf * 16 + li) * KTOT
                                            + ks * 32 + lg * 8);

    // batch ALL Z loads (4 cf x 6 ks), named registers
    const short* zpa = Zt + (size_t)(c0 + ch * 64 +  0 + li) * KTOT + lg * 8;
    const short* zpb = Zt + (size_t)(c0 + ch * 64 + 16 + li) * KTOT + lg * 8;
    const short* zpc = Zt + (size_t)(c0 + ch * 64 + 32 + li) * KTOT + lg * 8;
    const short* zpd = Zt + (size_t)(c0 + ch * 64 + 48 + li) * KTOT + lg * 8;
    s16x8 za0 = *(const s16x8*)(zpa),       za1 = *(const s16x8*)(zpa + 32);
    s16x8 za2 = *(const s16x8*)(zpa + 64),  za3 = *(const s16x8*)(zpa + 96);
    s16x8 za4 = *(const s16x8*)(zpa + 128), za5 = *(const s16x8*)(zpa + 160);
    s16x8 zb0 = *(const s16x8*)(zpb),       zb1 = *(const s16x8*)(zpb + 32);
    s16x8 zb2 = *(const s16x8*)(zpb + 64),  zb3 = *(const s16x8*)(zpb + 96);
    s16x8 zb4 = *(const s16x8*)(zpb + 128), zb5 = *(const s16x8*)(zpb + 160);
    s16x8 zc0 = *(const s16x8*)(zpc),       zc1 = *(const s16x8*)(zpc + 32);
    s16x8 zc2 = *(const s16x8*)(zpc + 64),  zc3 = *(const s16x8*)(zpc + 96);
    s16x8 zc4 = *(const s16x8*)(zpc + 128), zc5 = *(const s16x8*)(zpc + 160);
    s16x8 zd0 = *(const s16x8*)(zpd),       zd1 = *(const s16x8*)(zpd + 32);
    s16x8 zd2 = *(const s16x8*)(zpd + 64),  zd3 = *(const s16x8*)(zpd + 96);
    s16x8 zd4 = *(const s16x8*)(zpd + 128), zd5 = *(const s16x8*)(zpd + 160);

    f32x4 aA0 = {0,0,0,0}, aA1 = {0,0,0,0};
    f32x4 aB0 = {0,0,0,0}, aB1 = {0,0,0,0};
    f32x4 aC0 = {0,0,0,0}, aC1 = {0,0,0,0};
    f32x4 aD0 = {0,0,0,0}, aD1 = {0,0,0,0};
    #pragma unroll
    for (int ks = 0; ks < 6; ++ks) {
        s16x8 za = (ks==0)?za0:(ks==1)?za1:(ks==2)?za2:(ks==3)?za3:(ks==4)?za4:za5;
        s16x8 zb = (ks==0)?zb0:(ks==1)?zb1:(ks==2)?zb2:(ks==3)?zb3:(ks==4)?zb4:zb5;
        s16x8 zc = (ks==0)?zc0:(ks==1)?zc1:(ks==2)?zc2:(ks==3)?zc3:(ks==4)?zc4:zc5;
        s16x8 zd = (ks==0)?zd0:(ks==1)?zd1:(ks==2)?zd2:(ks==3)?zd3:(ks==4)?zd4:zd5;
        aA0 = __builtin_amdgcn_mfma_f32_16x16x32_bf16(wf[0][ks], za, aA0, 0, 0, 0);
        aA1 = __builtin_amdgcn_mfma_f32_16x16x32_bf16(wf[1][ks], za, aA1, 0, 0, 0);
        aB0 = __builtin_amdgcn_mfma_f32_16x16x32_bf16(wf[0][ks], zb, aB0, 0, 0, 0);
        aB1 = __builtin_amdgcn_mfma_f32_16x16x32_bf16(wf[1][ks], zb, aB1, 0, 0, 0);
        aC0 = __builtin_amdgcn_mfma_f32_16x16x32_bf16(wf[0][ks], zc, aC0, 0, 0, 0);
        aC1 = __builtin_amdgcn_mfma_f32_16x16x32_bf16(wf[1][ks], zc, aC1, 0, 0, 0);
        aD0 = __builtin_amdgcn_mfma_f32_16x16x32_bf16(wf[0][ks], zd, aD0, 0, 0, 0);
        aD1 = __builtin_amdgcn_mfma_f32_16x16x32_bf16(wf[1][ks], zd, aD1, 0, 0, 0);
    }

    const float* bsum = ws + WS_BSUM;
    #pragma unroll
    for (int mf = 0; mf < 2; ++mf) {
        #pragma unroll
        for (int r = 0; r < 4; ++r) {
            int o = o0 + mf * 16 + lg * 4 + r;
            float bo = bsum[o];
            float vA = (mf ? aA1[r] : aA0[r]) + bo;
            float vB = (mf ? aB1[r] : aB0[r]) + bo;
            float vC = (mf ? aC1[r] : aC0[r]) + bo;
            float vD = (mf ? aD1[r] : aD0[r]) + bo;
            float s  = vA + vB + vC + vD;
            float sq = vA * vA + vB * vB + vC * vC + vD * vD;
            #pragma unroll
            for (int m = 1; m < 16; m <<= 1) {
                s  += __shfl_xor(s, m, 64);
                sq += __shfl_xor(sq, m, 64);
            }
            if (li == 0) {
                atomicAdd(&sstat[o], s);
                atomicAdd(&sstat[128 + o], sq);
            }
        }
    }
    __syncthreads();
    if (tid < 256) ws[WS_PART + blockIdx.x * 256 + tid] = sstat[tid];
}

__global__ void finalize_partials(const float* __restrict__ gamma,
                                  const float* __restrict__ beta,
                                  float* ws) {
    __shared__ float red[2];
    const int o = blockIdx.x;
    const int wave = threadIdx.x >> 6;
    const int lane = threadIdx.x & 63;
    float acc = 0.f;
    #pragma unroll
    for (int it = 0; it < (SBLK + 63) / 64; ++it) {
        int blk = lane + it * 64;
        if (blk < SBLK) acc += ws[WS_PART + blk * 256 + wave * 128 + o];
    }
    #pragma unroll
    for (int m = 1; m < 64; m <<= 1) acc += __shfl_xor(acc, m, 64);
    if (lane == 0) red[wave] = acc;
    __syncthreads();
    if (threadIdx.x == 0) {
        float mean = red[0] * (1.0f / CNT);
        float ex2  = red[1] * (1.0f / CNT);
        float var  = ex2 - mean * mean;
        float rstd = rsqrtf(var + 1e-5f);
        float sc = gamma[o] * rstd;
        ws[WS_SCALE + o] = sc;
        ws[WS_SHIFT + o] = beta[o] - mean * sc;
    }
}

// conv_apply: Zt -> final y (BN+ReLU fused). 32-col blocks; per wave 6 batched
// Z loads + 12 MFMA; no LDS, no barriers; writes y exactly once.
__global__ __launch_bounds__(512, 4) void conv_apply(const short* __restrict__ Zt,
                                                     float* __restrict__ y,
                                                     const float* __restrict__ ws) {
    const int lane = threadIdx.x & 63;
    const int wave = threadIdx.x >> 6;
    const int lg = lane >> 4;
    const int li = lane & 15;
    const int c0 = blockIdx.x * 32;
    const int ow = wave >> 1;
    const int ch = wave & 1;
    const int o0 = ow * 32;
    const int col = c0 + ch * 16 + li;

    const short* zp = Zt + (size_t)col * KTOT + lg * 8;
    s16x8 z0 = *(const s16x8*)(zp),       z1 = *(const s16x8*)(zp + 32);
    s16x8 z2 = *(const s16x8*)(zp + 64),  z3 = *(const s16x8*)(zp + 96);
    s16x8 z4 = *(const s16x8*)(zp + 128), z5 = *(const s16x8*)(zp + 160);

    const short* w2 = (const short*)(ws + WS_W2);
    s16x8 wf[2][6];
    #pragma unroll
    for (int mf = 0; mf < 2; ++mf)
        #pragma unroll
        for (int ks = 0; ks < 6; ++ks)
            wf[mf][ks] = *(const s16x8*)(w2 + (o0 + mf * 16 + li) * KTOT
                                            + ks * 32 + lg * 8);

    f32x4 a0 = {0,0,0,0}, a1 = {0,0,0,0};
    a0 = __builtin_amdgcn_mfma_f32_16x16x32_bf16(wf[0][0], z0, a0, 0, 0, 0);
    a1 = __builtin_amdgcn_mfma_f32_16x16x32_bf16(wf[1][0], z0, a1, 0, 0, 0);
    a0 = __builtin_amdgcn_mfma_f32_16x16x32_bf16(wf[0][1], z1, a0, 0, 0, 0);
    a1 = __builtin_amdgcn_mfma_f32_16x16x32_bf16(wf[1][1], z1, a1, 0, 0, 0);
    a0 = __builtin_amdgcn_mfma_f32_16x16x32_bf16(wf[0][2], z2, a0, 0, 0, 0);
    a1 = __builtin_amdgcn_mfma_f32_16x16x32_bf16(wf[1][2], z2, a1, 0, 0, 0);
    a0 = __builtin_amdgcn_mfma_f32_16x16x32_bf16(wf[0][3], z3, a0, 0, 0, 0);
    a1 = __builtin_amdgcn_mfma_f32_16x16x32_bf16(wf[1][3], z3, a1, 0, 0, 0);
    a0 = __builtin_amdgcn_mfma_f32_16x16x32_bf16(wf[0][4], z4, a0, 0, 0, 0);
    a1 = __builtin_amdgcn_mfma_f32_16x16x32_bf16(wf[1][4], z4, a1, 0, 0, 0);
    a0 = __builtin_amdgcn_mfma_f32_16x16x32_bf16(wf[0][5], z5, a0, 0, 0, 0);
    a1 = __builtin_amdgcn_mfma_f32_16x16x32_bf16(wf[1][5], z5, a1, 0, 0, 0);

    const float* bsum  = ws + WS_BSUM;
    const float* scale = ws + WS_SCALE;
    const float* shift = ws + WS_SHIFT;
    const int nn = col / 7500;
    const int inner = col - nn * 7500;
    float* yb = y + (size_t)nn * COUT * 7500 + inner;
    #pragma unroll
    for (int mf = 0; mf < 2; ++mf) {
        float4 scv = *(const float4*)(scale + o0 + mf * 16 + lg * 4);
        float4 shv = *(const float4*)(shift + o0 + mf * 16 + lg * 4);
        float4 bov = *(const float4*)(bsum  + o0 + mf * 16 + lg * 4);
        float scr[4] = {scv.x, scv.y, scv.z, scv.w};
        float shr[4] = {shv.x, shv.y, shv.z, shv.w};
        float bor[4] = {bov.x, bov.y, bov.z, bov.w};
        #pragma unroll
        for (int r = 0; r < 4; ++r) {
            int o = o0 + mf * 16 + lg * 4 + r;
            float val = (mf ? a1[r] : a0[r]) + bor[r];
            val = fmaxf(val * scr[r] + shr[r], 0.0f);
            yb[(size_t)o * 7500] = val;
            yb += 0;  // no-op; address advanced via o
        }
    }
}

// ---------------- fallback path (R4) ----------------
__global__ __launch_bounds__(512, 4) void sgcn_main(const float* __restrict__ x,
                                                    const float* __restrict__ A,
                                                    float* __restrict__ y,
                                                    float* ws) {
    __shared__ __align__(16) short Xs[TTILE * 64 * XSTR];
    __shared__ __align__(16) short Ats[PP * 32 * XSTR];
    __shared__ __align__(16) short Z2s[ZROWS * ZSTR];
    __shared__ float sstat[256];

    const int tid  = threadIdx.x;
    const int lane = tid & 63;
    const int wave = tid >> 6;
    const int n  = blockIdx.x / NTILES;
    const int t0 = (blockIdx.x % NTILES) * TTILE;
    const int lg = lane >> 4;
    const int li = lane & 15;

    {
        const float* xb = x + (size_t)n * (CIN * TTOT * VV) + (size_t)t0 * VV;
        #pragma unroll
        for (int it = 0; it < 20; ++it) {
            int i = tid + it * 512;
            int c = i / 160;
            int r2 = i - c * 160;
            int t = r2 >> 5, w = r2 & 31;
            float val = (w < VV) ? xb[c * (TTOT * VV) + t * VV + w] : 0.0f;
            Xs[(t * 64 + c) * XSTR + w] = f2bf(val);
        }
        #pragma unroll
        for (int it = 0; it < 8; ++it) {
            int i = tid + it * 512;
            if (i < PP * 32 * XSTR) {
                int p = i / (32 * XSTR);
                int r = i - p * (32 * XSTR);
                int v = r / XSTR, w = r - v * XSTR;
                Ats[i] = (v < VV && w < VV) ? f2bf(A[p * (VV * VV) + w * VV + v])
                                            : (short)0;
            }
        }
        if (tid < 108) ((int*)(Z2s + 125 * ZSTR))[tid] = 0;
        if (tid < 256) sstat[tid] = 0.0f;
    }
    __syncthreads();

    const int ow = wave >> 1;
    const int cw = wave & 1;
    const int o0 = ow * 32;
    const short* w2 = (const short*)(ws + WS_W2);

    f32x4 acc[2][4];
    #pragma unroll
    for (int mf = 0; mf < 2; ++mf)
        #pragma unroll
        for (int cf = 0; cf < 4; ++cf)
            acc[mf][cf] = (f32x4){0.f, 0.f, 0.f, 0.f};

    for (int p = 0; p < PP; ++p) {
        s16x8 wfl[2][2];
        #pragma unroll
        for (int mf = 0; mf < 2; ++mf)
            #pragma unroll
            for (int ks = 0; ks < 2; ++ks)
                wfl[mf][ks] = *(const s16x8*)(w2 + (o0 + mf * 16 + li) * KTOT
                                                 + p * 64 + ks * 32 + lg * 8);
        #pragma unroll
        for (int q = 0; q < 5; ++q) {
            int f = wave * 5 + q;
            int t = f >> 3, rem = f & 7;
            int vf = rem >> 2, cfr = rem & 3;
            s16x8 af = *(const s16x8*)(&Ats[(p * 32 + vf * 16 + li) * XSTR + lg * 8]);
            s16x8 bf = *(const s16x8*)(&Xs[(t * 64 + cfr * 16 + li) * XSTR + lg * 8]);
            f32x4 z = (f32x4){0.f, 0.f, 0.f, 0.f};
            f32x4 d = __builtin_amdgcn_mfma_f32_16x16x32_bf16(af, bf, z, 0, 0, 0);
            int m0 = vf * 16 + lg * 4;
            int ccol = cfr * 16 + li;
            #pragma unroll
            for (int r = 0; r < 4; ++r) {
                int m = m0 + r;
                if (m < VV) Z2s[(t * VV + m) * ZSTR + ccol] = f2bf(d[r]);
            }
        }
        __syncthreads();
        #pragma unroll
        for (int cf = 0; cf < 4; ++cf) {
            int col0 = cw * 64 + cf * 16;
            #pragma unroll
            for (int ks = 0; ks < 2; ++ks) {
                s16x8 zf = *(const s16x8*)(&Z2s[(col0 + li) * ZSTR + ks * 32 + lg * 8]);
                #pragma unroll
                for (int mf = 0; mf < 2; ++mf)
                    acc[mf][cf] = __builtin_amdgcn_mfma_f32_16x16x32_bf16(
                        wfl[mf][ks], zf, acc[mf][cf], 0, 0, 0);
            }
        }
        __syncthreads();
    }

    const float* bsum = ws + WS_BSUM;
    #pragma unroll
    for (int mf = 0; mf < 2; ++mf) {
        #pragma unroll
        for (int r = 0; r < 4; ++r) {
            int o = o0 + mf * 16 + lg * 4 + r;
            float bo = bsum[o];
            float s = 0.f, sq = 0.f;
            #pragma unroll
            for (int cf = 0; cf < 4; ++cf) {
                int col = cw * 64 + cf * 16 + li;
                float val = acc[mf][cf][r] + bo;
                if (col < TTILE * VV) {
                    y[(size_t)(n * COUT + o) * (TTOT * VV) + t0 * VV + col] = val;
                    s += val; sq += val * val;
                }
            }
            #pragma unroll
            for (int m = 1; m < 16; m <<= 1) {
                s  += __shfl_xor(s, m, 64);
                sq += __shfl_xor(sq, m, 64);
            }
            if (li == 0) {
                atomicAdd(&sstat[o], s);
                atomicAdd(&sstat[128 + o], sq);
            }
        }
    }
    __syncthreads();
    if (tid < 256) atomicAdd(&ws[WS_STATS + tid], sstat[tid]);
}

__global__ void finalize_kernel(const float* __restrict__ gamma,
                                const float* __restrict__ beta,
                                float* ws) {
    int o = threadIdx.x;
    float mean = ws[WS_STATS + o] * (1.0f / CNT);
    float ex2  = ws[WS_STATS + 128 + o] * (1.0f / CNT);
    float var  = ex2 - mean * mean;
    float rstd = rsqrtf(var + 1e-5f);
    float sc = gamma[o] * rstd;
    ws[WS_SCALE + o] = sc;
    ws[WS_SHIFT + o] = beta[o] - mean * sc;
}

__global__ __launch_bounds__(256) void norm_relu_kernel(float* __restrict__ y,
                                                        const float* __restrict__ ws) {
    const int total8 = (NN * COUT * TTOT * VV) / 8;
    const float* scale = ws + WS_SCALE;
    const float* shift = ws + WS_SHIFT;
    for (int i = blockIdx.x * blockDim.x + threadIdx.x; i < total8;
         i += gridDim.x * blockDim.x) {
        size_t base = (size_t)i * 8;
        int row0 = (int)(base / 7500);
        int row1 = (int)((base + 7) / 7500);
        int o0 = row0 & 127, o1 = row1 & 127;
        float s0 = scale[o0], h0 = shift[o0];
        float s1 = scale[o1], h1 = shift[o1];
        size_t bnd = (size_t)(row0 + 1) * 7500;
        float4 a = *(const float4*)(y + base);
        float4 b = *(const float4*)(y + base + 4);
        float vals[8] = {a.x, a.y, a.z, a.w, b.x, b.y, b.z, b.w};
        #pragma unroll
        for (int e = 0; e < 8; ++e) {
            bool first = (base + (size_t)e) < bnd;
            float sv = first ? s0 : s1;
            float hv = first ? h0 : h1;
            vals[e] = fmaxf(vals[e] * sv + hv, 0.0f);
        }
        a = make_float4(vals[0], vals[1], vals[2], vals[3]);
        b = make_float4(vals[4], vals[5], vals[6], vals[7]);
        *(float4*)(y + base) = a;
        *(float4*)(y + base + 4) = b;
    }
}

extern "C" void kernel_launch(void* const* d_in, const int* in_sizes, int n_in,
                              void* d_out, int out_size, void* d_ws, size_t ws_size,
                              hipStream_t stream) {
    const float* x     = (const float*)d_in[0];
    const float* A     = (const float*)d_in[1];
    const float* W     = (const float*)d_in[2];
    const float* b     = (const float*)d_in[3];
    const float* gamma = (const float*)d_in[4];
    const float* beta  = (const float*)d_in[5];
    float* y  = (float*)d_out;
    float* ws = (float*)d_ws;

    prep_kernel<<<96, 256, 0, stream>>>(W, A, b, ws);
    if (ws_size >= WS_NEEDED) {
        short* Zt = (short*)((char*)d_ws + ZT_BYTE_OFF);
        agg_v2<<<NBLK, 512, 0, stream>>>(x, ws, Zt);
        conv_stats<<<SBLK, 512, 0, stream>>>(Zt, ws);
        finalize_partials<<<COUT, 128, 0, stream>>>(gamma, beta, ws);
        conv_apply<<<ABLK, 512, 0, stream>>>(Zt, y, ws);
    } else {
        sgcn_main<<<NN * NTILES, 512, 0, stream>>>(x, A, y, ws);
        finalize_kernel<<<1, 128, 0, stream>>>(gamma, beta, ws);
        norm_relu_kernel<<<2048, 256, 0, stream>>>(y, ws);
    }
}

// Round 10
// 165.655 us; speedup vs baseline: 1.6991x; 1.6991x over previous
//
#include <hip/hip_runtime.h>
#include <hip/hip_bf16.h>

#define NN 32
#define CIN 64
#define TTOT 300
#define VV 25
#define PP 3
#define COUT 128
#define KTOT 192     // P*CIN
#define TTILE 5
#define NTILES 60
#define CNT 240000.0f
#define NCOLS 240000
#define NBLK 1920    // agg/conv grid: 125 real cols (+3 pad) per block

#define XSTR 40      // fallback path stride
#define ZSTR 72
#define ZROWS 128
#define ZFB 49152    // bytes per Zf tile: 48 frags x 1KB

// ws float offsets (front region)
#define WS_STATS 0    // 256 f32 (fallback path only)
#define WS_SCALE 256  // 128 f32
#define WS_SHIFT 384  // 128 f32
#define WS_BSUM  512  // 128 f32
#define WS_W2    640  // bf16[128*192] old layout (fallback path)
#define WS_AT    16384            // bf16[3*32*40] At table (zero-padded)
#define WS_W2F   20480            // bf16 fragment-major W (49152 B), ends at f32 32768
#define WS_PART  36864            // f32[1920][256] partials, ends ~2.1 MB
#define ZT_BYTE_OFF (5u << 19)    // Zf at +2.5MB
#define WS_NEEDED (ZT_BYTE_OFF + (size_t)NBLK * ZFB)   // ~96.9 MB

typedef float f32x4 __attribute__((ext_vector_type(4)));
typedef short s16x8 __attribute__((ext_vector_type(8)));

__device__ __forceinline__ short f2bf(float f) {
    unsigned u = __float_as_uint(f);
    u += 0x7fff + ((u >> 16) & 1);          // RNE
    return (short)(u >> 16);
}

__global__ __launch_bounds__(256) void prep_kernel(const float* __restrict__ W,
                                                   const float* __restrict__ A,
                                                   const float* __restrict__ b,
                                                   float* __restrict__ ws) {
    int tid = blockIdx.x * blockDim.x + threadIdx.x;
    if (tid < 256) ws[WS_STATS + tid] = 0.0f;               // fallback path zeroing
    if (tid >= 256 && tid < 384) {
        int o = tid - 256;
        ws[WS_BSUM + o] = b[o] + b[COUT + o] + b[2 * COUT + o];
    }
    if (tid < COUT * KTOT) {                                 // old W2[o][k] (fallback)
        int o = tid / KTOT, k = tid % KTOT;
        int p = k / 64, c = k % 64;
        ((short*)(ws + WS_W2))[tid] = f2bf(W[(p * COUT + o) * CIN + c]);
    }
    if (tid < PP * 32 * XSTR) {                              // At[p][v][w], zero-padded
        int p = tid / (32 * XSTR);
        int r = tid - p * (32 * XSTR);
        int v = r / XSTR, w = r - v * XSTR;
        ((short*)(ws + WS_AT))[tid] =
            (v < VV && w < VV) ? f2bf(A[p * (VV * VV) + w * VV + v]) : (short)0;
    }
    if (tid < 3072) {                                        // W2f fragment-major
        // chunk c: ofrag=c/384, ks=(c/64)%6, lane=c&63 -> li=lane&15, lg=lane>>4
        int c = tid;
        int ofrag = c / 384;
        int rem = c - ofrag * 384;
        int ks = rem >> 6;
        int l = rem & 63;
        int li = l & 15, lg = l >> 4;
        int o = ofrag * 16 + li;
        int kb = ks * 32 + lg * 8;
        short* dst = (short*)((char*)(ws + WS_W2F) + c * 16);
        #pragma unroll
        for (int e = 0; e < 8; ++e) {
            int k = kb + e;
            int p = k >> 6, cc = k & 63;
            dst[e] = f2bf(W[(p * COUT + o) * CIN + cc]);
        }
    }
}

// ---------------- fast path ----------------

// agg_v3: x -> Zf (fragment-major) via LDS. LDS 48KB (XF unioned with Zf tile)
// -> 3 blocks/CU. Coalesced x staging; coalesced 48KB copy-out.
__global__ __launch_bounds__(512, 4) void agg_v3(const float* __restrict__ x,
                                                 const float* __restrict__ ws,
                                                 char* __restrict__ Zf) {
    __shared__ __align__(16) char SM[ZFB];     // phase A/B: XF f32 tile; C/D: Zf tile
    float* XF = (float*)SM;

    const int tid  = threadIdx.x;
    const int lane = tid & 63;
    const int wave = tid >> 6;
    const int n  = blockIdx.x / NTILES;
    const int t0 = (blockIdx.x % NTILES) * TTILE;
    const int lg = lane >> 4;
    const int li = lane & 15;

    // ---- phase A: stage x raw f32, XOR-swizzled; w>=25 zeroed (K-pad) ----
    {
        const float* xb = x + (size_t)n * (CIN * TTOT * VV) + (size_t)t0 * VV;
        #pragma unroll
        for (int it = 0; it < 20; ++it) {                   // 20*512 = 64*5*32
            int i = tid + it * 512;
            int c = i / 160;
            int r2 = i - c * 160;
            int t = r2 >> 5, w = r2 & 31;
            float val = (w < VV) ? xb[c * (TTOT * VV) + t * VV + w] : 0.0f;
            int row = t * 64 + c;
            int byte = ((row * 32 + w) * 4) ^ ((row & 7) << 4);
            *(float*)((char*)XF + byte) = val;
        }
    }
    __syncthreads();

    // ---- phase B: fragment reads into registers (XF dead afterwards) ----
    const int acf = wave >> 1;         // c-frag 0..3
    const int avf = wave & 1;          // v-frag 0..1
    const int vv  = avf * 16 + li;

    s16x8 xa[TTILE];
    #pragma unroll
    for (int t = 0; t < TTILE; ++t) {
        int row = t * 64 + acf * 16 + li;
        int sw = (row & 7) << 4;
        f32x4 lo = *(const f32x4*)((const char*)XF + ((row * 128 + lg * 32) ^ sw));
        f32x4 hi = *(const f32x4*)((const char*)XF + ((row * 128 + lg * 32 + 16) ^ sw));
        s16x8 v;
        v[0] = f2bf(lo[0]); v[1] = f2bf(lo[1]); v[2] = f2bf(lo[2]); v[3] = f2bf(lo[3]);
        v[4] = f2bf(hi[0]); v[5] = f2bf(hi[1]); v[6] = f2bf(hi[2]); v[7] = f2bf(hi[3]);
        xa[t] = v;
    }
    const short* at = (const short*)(ws + WS_AT);
    s16x8 af[PP];
    #pragma unroll
    for (int p = 0; p < PP; ++p)
        af[p] = *(const s16x8*)(at + (p * 32 + avf * 16 + li) * XSTR + lg * 8);
    __syncthreads();   // all waves done with XF before Zf-tile writes

    // ---- phase C: MFMAs -> LDS in Zf fragment order; zero pad chunks ----
    // chunk(col,oct) at byte ((col>>4)*6 + oct>>2)*1024 + (oct&3)*256 + (col&15)*16
    const bool vok = (vv < VV);
    #pragma unroll
    for (int t = 0; t < TTILE; ++t) {
        #pragma unroll
        for (int p = 0; p < PP; ++p) {
            f32x4 z = (f32x4){0.f, 0.f, 0.f, 0.f};
            f32x4 d = __builtin_amdgcn_mfma_f32_16x16x32_bf16(xa[t], af[p], z, 0, 0, 0);
            if (vok) {
                ushort4 pk;
                pk.x = (unsigned short)f2bf(d[0]);
                pk.y = (unsigned short)f2bf(d[1]);
                pk.z = (unsigned short)f2bf(d[2]);
                pk.w = (unsigned short)f2bf(d[3]);
                int col = t * VV + vv;                         // 0..124
                int oct = p * 8 + acf * 2 + (lg >> 1);         // k>>3
                int byte = (((col >> 4) * 6 + (oct >> 2)) << 10)
                         + ((oct & 3) << 8) + ((col & 15) << 4) + ((lg & 1) << 3);
                *(ushort4*)(SM + byte) = pk;
            }
        }
    }
    // zero pad cols 125..127 (colblk 7, li 13..15, all ks/lgf): 72 chunks
    if (tid < 288) {
        int ci = tid >> 2;
        int ks = ci / 12, r = ci - ks * 12;
        int lgf = r / 3, lif = 13 + (r - lgf * 3);
        int byte = (((42 + ks) << 6) + (lgf << 4) + lif) * 16 + ((tid & 3) << 2);
        *(int*)(SM + byte) = 0;
    }
    __syncthreads();

    // ---- phase D: coalesced copy-out (LDS verbatim -> Zf tile) ----
    {
        char* dst = Zf + (size_t)blockIdx.x * ZFB;
        #pragma unroll
        for (int i = 0; i < 6; ++i) {
            int c = tid + i * 512;
            *(s16x8*)(dst + c * 16) = *(const s16x8*)(SM + c * 16);
        }
    }
}

// conv_stats: Zf tile -> per-block partial sum/sumsq. All 36 fragment loads are
// single contiguous 1KB transactions, pinned before the MFMAs via sched_barrier.
__global__ __launch_bounds__(512, 2) void conv_stats(const char* __restrict__ Zf,
                                                     float* __restrict__ ws) {
    __shared__ float sstat[256];
    const int tid  = threadIdx.x;
    const int lane = tid & 63;
    const int wave = tid >> 6;
    const int lg = lane >> 4;
    const int li = lane & 15;
    const int ow = wave >> 1;
    const int ch = wave & 1;
    const int o0 = ow * 32;

    if (tid < 256) sstat[tid] = 0.0f;

    const char* zt = Zf + (size_t)blockIdx.x * ZFB;
    const char* wt = (const char*)(ws + WS_W2F);

    s16x8 wf[2][6];
    #pragma unroll
    for (int mf = 0; mf < 2; ++mf)
        #pragma unroll
        for (int ks = 0; ks < 6; ++ks)
            wf[mf][ks] = *(const s16x8*)(wt + ((((ow * 2 + mf) * 6 + ks) << 10)
                                              + lane * 16));
    s16x8 zf[4][6];
    #pragma unroll
    for (int cb = 0; cb < 4; ++cb)
        #pragma unroll
        for (int ks = 0; ks < 6; ++ks)
            zf[cb][ks] = *(const s16x8*)(zt + ((((ch * 4 + cb) * 6 + ks) << 10)
                                               + lane * 16));
    __builtin_amdgcn_sched_barrier(0);   // keep all loads hoisted above MFMAs

    f32x4 acc[2][4];
    #pragma unroll
    for (int mf = 0; mf < 2; ++mf)
        #pragma unroll
        for (int cb = 0; cb < 4; ++cb)
            acc[mf][cb] = (f32x4){0.f, 0.f, 0.f, 0.f};

    #pragma unroll
    for (int ks = 0; ks < 6; ++ks)
        #pragma unroll
        for (int cb = 0; cb < 4; ++cb) {
            acc[0][cb] = __builtin_amdgcn_mfma_f32_16x16x32_bf16(wf[0][ks], zf[cb][ks],
                                                                 acc[0][cb], 0, 0, 0);
            acc[1][cb] = __builtin_amdgcn_mfma_f32_16x16x32_bf16(wf[1][ks], zf[cb][ks],
                                                                 acc[1][cb], 0, 0, 0);
        }

    const float* bsum = ws + WS_BSUM;
    #pragma unroll
    for (int mf = 0; mf < 2; ++mf) {
        #pragma unroll
        for (int r = 0; r < 4; ++r) {
            int o = o0 + mf * 16 + lg * 4 + r;
            float bo = bsum[o];
            float s = 0.f, sq = 0.f;
            #pragma unroll
            for (int cb = 0; cb < 4; ++cb) {
                int lcol = ch * 64 + cb * 16 + li;
                if (lcol < TTILE * VV) {
                    float val = acc[mf][cb][r] + bo;
                    s += val; sq += val * val;
                }
            }
            #pragma unroll
            for (int m = 1; m < 16; m <<= 1) {
                s  += __shfl_xor(s, m, 64);
                sq += __shfl_xor(sq, m, 64);
            }
            if (li == 0) {
                atomicAdd(&sstat[o], s);
                atomicAdd(&sstat[128 + o], sq);
            }
        }
    }
    __syncthreads();
    if (tid < 256) ws[WS_PART + blockIdx.x * 256 + tid] = sstat[tid];
}

__global__ void finalize_partials(const float* __restrict__ gamma,
                                  const float* __restrict__ beta,
                                  float* ws) {
    __shared__ float red[2];
    const int o = blockIdx.x;
    const int wave = threadIdx.x >> 6;
    const int lane = threadIdx.x & 63;
    float acc = 0.f;
    #pragma unroll
    for (int it = 0; it < NBLK / 64; ++it) {
        int blk = lane + it * 64;
        acc += ws[WS_PART + blk * 256 + wave * 128 + o];
    }
    #pragma unroll
    for (int m = 1; m < 64; m <<= 1) acc += __shfl_xor(acc, m, 64);
    if (lane == 0) red[wave] = acc;
    __syncthreads();
    if (threadIdx.x == 0) {
        float mean = red[0] * (1.0f / CNT);
        float ex2  = red[1] * (1.0f / CNT);
        float var  = ex2 - mean * mean;
        float rstd = rsqrtf(var + 1e-5f);
        float sc = gamma[o] * rstd;
        ws[WS_SCALE + o] = sc;
        ws[WS_SHIFT + o] = beta[o] - mean * sc;
    }
}

// conv_apply: Zf tile -> final y (BN+ReLU fused), written exactly once.
__global__ __launch_bounds__(512, 2) void conv_apply(const char* __restrict__ Zf,
                                                     float* __restrict__ y,
                                                     const float* __restrict__ ws) {
    const int lane = threadIdx.x & 63;
    const int wave = threadIdx.x >> 6;
    const int lg = lane >> 4;
    const int li = lane & 15;
    const int ow = wave >> 1;
    const int ch = wave & 1;
    const int o0 = ow * 32;
    const int n  = blockIdx.x / NTILES;
    const int tb = blockIdx.x % NTILES;

    const char* zt = Zf + (size_t)blockIdx.x * ZFB;
    const char* wt = (const char*)(ws + WS_W2F);

    s16x8 wf[2][6];
    #pragma unroll
    for (int mf = 0; mf < 2; ++mf)
        #pragma unroll
        for (int ks = 0; ks < 6; ++ks)
            wf[mf][ks] = *(const s16x8*)(wt + ((((ow * 2 + mf) * 6 + ks) << 10)
                                              + lane * 16));
    s16x8 zf[4][6];
    #pragma unroll
    for (int cb = 0; cb < 4; ++cb)
        #pragma unroll
        for (int ks = 0; ks < 6; ++ks)
            zf[cb][ks] = *(const s16x8*)(zt + ((((ch * 4 + cb) * 6 + ks) << 10)
                                               + lane * 16));
    __builtin_amdgcn_sched_barrier(0);

    f32x4 acc[2][4];
    #pragma unroll
    for (int mf = 0; mf < 2; ++mf)
        #pragma unroll
        for (int cb = 0; cb < 4; ++cb)
            acc[mf][cb] = (f32x4){0.f, 0.f, 0.f, 0.f};

    #pragma unroll
    for (int ks = 0; ks < 6; ++ks)
        #pragma unroll
        for (int cb = 0; cb < 4; ++cb) {
            acc[0][cb] = __builtin_amdgcn_mfma_f32_16x16x32_bf16(wf[0][ks], zf[cb][ks],
                                                                 acc[0][cb], 0, 0, 0);
            acc[1][cb] = __builtin_amdgcn_mfma_f32_16x16x32_bf16(wf[1][ks], zf[cb][ks],
                                                                 acc[1][cb], 0, 0, 0);
        }

    const float* bsum  = ws + WS_BSUM;
    const float* scale = ws + WS_SCALE;
    const float* shift = ws + WS_SHIFT;
    float* yb = y + (size_t)n * COUT * 7500 + tb * (TTILE * VV);
    #pragma unroll
    for (int mf = 0; mf < 2; ++mf) {
        #pragma unroll
        for (int r = 0; r < 4; ++r) {
            int o = o0 + mf * 16 + lg * 4 + r;
            float bo = bsum[o];
            float sc = scale[o];
            float sh = shift[o];
            #pragma unroll
            for (int cb = 0; cb < 4; ++cb) {
                int lcol = ch * 64 + cb * 16 + li;
                if (lcol < TTILE * VV) {
                    float val = acc[mf][cb][r] + bo;
                    val = fmaxf(val * sc + sh, 0.0f);
                    yb[(size_t)o * 7500 + lcol] = val;
                }
            }
        }
    }
}

// ---------------- fallback path (R4) ----------------
__global__ __launch_bounds__(512, 4) void sgcn_main(const float* __restrict__ x,
                                                    const float* __restrict__ A,
                                                    float* __restrict__ y,
                                                    float* ws) {
    __shared__ __align__(16) short Xs[TTILE * 64 * XSTR];
    __shared__ __align__(16) short Ats[PP * 32 * XSTR];
    __shared__ __align__(16) short Z2s[ZROWS * ZSTR];
    __shared__ float sstat[256];

    const int tid  = threadIdx.x;
    const int lane = tid & 63;
    const int wave = tid >> 6;
    const int n  = blockIdx.x / NTILES;
    const int t0 = (blockIdx.x % NTILES) * TTILE;
    const int lg = lane >> 4;
    const int li = lane & 15;

    {
        const float* xb = x + (size_t)n * (CIN * TTOT * VV) + (size_t)t0 * VV;
        #pragma unroll
        for (int it = 0; it < 20; ++it) {
            int i = tid + it * 512;
            int c = i / 160;
            int r2 = i - c * 160;
            int t = r2 >> 5, w = r2 & 31;
            float val = (w < VV) ? xb[c * (TTOT * VV) + t * VV + w] : 0.0f;
            Xs[(t * 64 + c) * XSTR + w] = f2bf(val);
        }
        #pragma unroll
        for (int it = 0; it < 8; ++it) {
            int i = tid + it * 512;
            if (i < PP * 32 * XSTR) {
                int p = i / (32 * XSTR);
                int r = i - p * (32 * XSTR);
                int v = r / XSTR, w = r - v * XSTR;
                Ats[i] = (v < VV && w < VV) ? f2bf(A[p * (VV * VV) + w * VV + v])
                                            : (short)0;
            }
        }
        if (tid < 108) ((int*)(Z2s + 125 * ZSTR))[tid] = 0;
        if (tid < 256) sstat[tid] = 0.0f;
    }
    __syncthreads();

    const int ow = wave >> 1;
    const int cw = wave & 1;
    const int o0 = ow * 32;
    const short* w2 = (const short*)(ws + WS_W2);

    f32x4 acc[2][4];
    #pragma unroll
    for (int mf = 0; mf < 2; ++mf)
        #pragma unroll
        for (int cf = 0; cf < 4; ++cf)
            acc[mf][cf] = (f32x4){0.f, 0.f, 0.f, 0.f};

    for (int p = 0; p < PP; ++p) {
        s16x8 wfl[2][2];
        #pragma unroll
        for (int mf = 0; mf < 2; ++mf)
            #pragma unroll
            for (int ks = 0; ks < 2; ++ks)
                wfl[mf][ks] = *(const s16x8*)(w2 + (o0 + mf * 16 + li) * KTOT
                                                 + p * 64 + ks * 32 + lg * 8);
        #pragma unroll
        for (int q = 0; q < 5; ++q) {
            int f = wave * 5 + q;
            int t = f >> 3, rem = f & 7;
            int vf = rem >> 2, cfr = rem & 3;
            s16x8 af = *(const s16x8*)(&Ats[(p * 32 + vf * 16 + li) * XSTR + lg * 8]);
            s16x8 bf = *(const s16x8*)(&Xs[(t * 64 + cfr * 16 + li) * XSTR + lg * 8]);
            f32x4 z = (f32x4){0.f, 0.f, 0.f, 0.f};
            f32x4 d = __builtin_amdgcn_mfma_f32_16x16x32_bf16(af, bf, z, 0, 0, 0);
            int m0 = vf * 16 + lg * 4;
            int ccol = cfr * 16 + li;
            #pragma unroll
            for (int r = 0; r < 4; ++r) {
                int m = m0 + r;
                if (m < VV) Z2s[(t * VV + m) * ZSTR + ccol] = f2bf(d[r]);
            }
        }
        __syncthreads();
        #pragma unroll
        for (int cf = 0; cf < 4; ++cf) {
            int col0 = cw * 64 + cf * 16;
            #pragma unroll
            for (int ks = 0; ks < 2; ++ks) {
                s16x8 zfr = *(const s16x8*)(&Z2s[(col0 + li) * ZSTR + ks * 32 + lg * 8]);
                #pragma unroll
                for (int mf = 0; mf < 2; ++mf)
                    acc[mf][cf] = __builtin_amdgcn_mfma_f32_16x16x32_bf16(
                        wfl[mf][ks], zfr, acc[mf][cf], 0, 0, 0);
            }
        }
        __syncthreads();
    }

    const float* bsum = ws + WS_BSUM;
    #pragma unroll
    for (int mf = 0; mf < 2; ++mf) {
        #pragma unroll
        for (int r = 0; r < 4; ++r) {
            int o = o0 + mf * 16 + lg * 4 + r;
            float bo = bsum[o];
            float s = 0.f, sq = 0.f;
            #pragma unroll
            for (int cf = 0; cf < 4; ++cf) {
                int col = cw * 64 + cf * 16 + li;
                float val = acc[mf][cf][r] + bo;
                if (col < TTILE * VV) {
                    y[(size_t)(n * COUT + o) * (TTOT * VV) + t0 * VV + col] = val;
                    s += val; sq += val * val;
                }
            }
            #pragma unroll
            for (int m = 1; m < 16; m <<= 1) {
                s  += __shfl_xor(s, m, 64);
                sq += __shfl_xor(sq, m, 64);
            }
            if (li == 0) {
                atomicAdd(&sstat[o], s);
                atomicAdd(&sstat[128 + o], sq);
            }
        }
    }
    __syncthreads();
    if (tid < 256) atomicAdd(&ws[WS_STATS + tid], sstat[tid]);
}

__global__ void finalize_kernel(const float* __restrict__ gamma,
                                const float* __restrict__ beta,
                                float* ws) {
    int o = threadIdx.x;
    float mean = ws[WS_STATS + o] * (1.0f / CNT);
    float ex2  = ws[WS_STATS + 128 + o] * (1.0f / CNT);
    float var  = ex2 - mean * mean;
    float rstd = rsqrtf(var + 1e-5f);
    float sc = gamma[o] * rstd;
    ws[WS_SCALE + o] = sc;
    ws[WS_SHIFT + o] = beta[o] - mean * sc;
}

__global__ __launch_bounds__(256) void norm_relu_kernel(float* __restrict__ y,
                                                        const float* __restrict__ ws) {
    const int total8 = (NN * COUT * TTOT * VV) / 8;
    const float* scale = ws + WS_SCALE;
    const float* shift = ws + WS_SHIFT;
    for (int i = blockIdx.x * blockDim.x + threadIdx.x; i < total8;
         i += gridDim.x * blockDim.x) {
        size_t base = (size_t)i * 8;
        int row0 = (int)(base / 7500);
        int row1 = (int)((base + 7) / 7500);
        int o0 = row0 & 127, o1 = row1 & 127;
        float s0 = scale[o0], h0 = shift[o0];
        float s1 = scale[o1], h1 = shift[o1];
        size_t bnd = (size_t)(row0 + 1) * 7500;
        float4 a = *(const float4*)(y + base);
        float4 b = *(const float4*)(y + base + 4);
        float vals[8] = {a.x, a.y, a.z, a.w, b.x, b.y, b.z, b.w};
        #pragma unroll
        for (int e = 0; e < 8; ++e) {
            bool first = (base + (size_t)e) < bnd;
            float sv = first ? s0 : s1;
            float hv = first ? h0 : h1;
            vals[e] = fmaxf(vals[e] * sv + hv, 0.0f);
        }
        a = make_float4(vals[0], vals[1], vals[2], vals[3]);
        b = make_float4(vals[4], vals[5], vals[6], vals[7]);
        *(float4*)(y + base) = a;
        *(float4*)(y + base + 4) = b;
    }
}

extern "C" void kernel_launch(void* const* d_in, const int* in_sizes, int n_in,
                              void* d_out, int out_size, void* d_ws, size_t ws_size,
                              hipStream_t stream) {
    const float* x     = (const float*)d_in[0];
    const float* A     = (const float*)d_in[1];
    const float* W     = (const float*)d_in[2];
    const float* b     = (const float*)d_in[3];
    const float* gamma = (const float*)d_in[4];
    const float* beta  = (const float*)d_in[5];
    float* y  = (float*)d_out;
    float* ws = (float*)d_ws;

    prep_kernel<<<96, 256, 0, stream>>>(W, A, b, ws);
    if (ws_size >= WS_NEEDED) {
        char* Zf = (char*)d_ws + ZT_BYTE_OFF;
        agg_v3<<<NBLK, 512, 0, stream>>>(x, ws, Zf);
        conv_stats<<<NBLK, 512, 0, stream>>>(Zf, ws);
        finalize_partials<<<COUT, 128, 0, stream>>>(gamma, beta, ws);
        conv_apply<<<NBLK, 512, 0, stream>>>(Zf, y, ws);
    } else {
        sgcn_main<<<NN * NTILES, 512, 0, stream>>>(x, A, y, ws);
        finalize_kernel<<<1, 128, 0, stream>>>(gamma, beta, ws);
        norm_relu_kernel<<<2048, 256, 0, stream>>>(y, ws);
    }
}